// Round 17
// baseline (296.764 us; speedup 1.0000x reference)
//
#include <hip/hip_runtime.h>
#include <math.h>

#define BB 8
#define NN 2048
#define FIN 128
#define FOUT 64
#define TIW 8             // rows per 1-wave block
#define TJ 256
#define TJP (TJ + 8)      // +8 bf16 = 16B row pad (verified skew family)
#define NTILE (NN / TJ)   // 8 j-tiles, looped inside the wave

typedef short bf16x8 __attribute__((ext_vector_type(8)));
typedef float f32x4 __attribute__((ext_vector_type(4)));

// exp(tanh(z)) = exp((u-1)/(u+1)), u = e^{2z}; v_rcp instead of precise div.
__device__ __forceinline__ float exp_tanh(float z) {
    float zc = fminf(fmaxf(z, -15.f), 15.f);
    float u = __expf(zc + zc);
    float tn = (u - 1.f) * __builtin_amdgcn_rcpf(u + 1.f);
    return __expf(tn);
}

__device__ __forceinline__ unsigned short f2bf(float x) {
    union { float f; unsigned u; } v; v.f = x;
    unsigned r = v.u + 0x7FFF + ((v.u >> 16) & 1);   // round-to-nearest-even
    return (unsigned short)(r >> 16);
}

// K1: h = x @ W -> bf16 TRANSPOSED ht[b][c][n]; f1 = h.a1, f2 = h.a2.
// (verbatim from the harness-verified kernel)
__global__ __launch_bounds__(256, 2) void gat_k1(const float* __restrict__ x,
                                                 const float* __restrict__ W,
                                                 const float* __restrict__ a,
                                                 unsigned short* __restrict__ ht,
                                                 float* __restrict__ f1,
                                                 float* __restrict__ f2) {
    __shared__ __attribute__((aligned(16))) float Wl[FIN][FOUT];  // 32 KB
    __shared__ __attribute__((aligned(16))) float xs[16][FIN];    // 8 KB
    int t = threadIdx.x;

    const float4* W4 = (const float4*)W;
    float4* Wl4 = (float4*)&Wl[0][0];
#pragma unroll
    for (int kk = 0; kk < 8; ++kk) Wl4[t + 256 * kk] = W4[t + 256 * kk];

    size_t row0 = (size_t)blockIdx.x * 16;
    const float4* x4 = (const float4*)(x + row0 * FIN);
    float4* xs4 = (float4*)&xs[0][0];
#pragma unroll
    for (int kk = 0; kk < 2; ++kk) xs4[t + 256 * kk] = x4[t + 256 * kk];
    __syncthreads();

    int c = t & 63;
    int rq = t >> 6;
    float acc[4] = {0.f, 0.f, 0.f, 0.f};
#pragma unroll 8
    for (int k = 0; k < FIN; ++k) {
        float wv = Wl[k][c];
        acc[0] = fmaf(xs[rq][k], wv, acc[0]);
        acc[1] = fmaf(xs[rq + 4][k], wv, acc[1]);
        acc[2] = fmaf(xs[rq + 8][k], wv, acc[2]);
        acc[3] = fmaf(xs[rq + 12][k], wv, acc[3]);
    }
    float a1c = a[c], a2c = a[FOUT + c];
#pragma unroll
    for (int m = 0; m < 4; ++m) {
        size_t bn = row0 + rq + 4 * m;
        int b = (int)(bn >> 11);
        int n = (int)(bn & 2047);
        ht[((size_t)b * FOUT + c) * NN + n] = f2bf(acc[m]);
        float p1 = acc[m] * a1c;
        float p2 = acc[m] * a2c;
#pragma unroll
        for (int off = 32; off > 0; off >>= 1) {
            p1 += __shfl_down(p1, off, 64);
            p2 += __shfl_down(p2, off, 64);
        }
        if (c == 0) { f1[bn] = p1; f2[bn] = p2; }
    }
}

// K2w R19: ONE WAVE PER BLOCK -- zero barriers.
// Ledger: R15 traffic/32 = +28 (not BW). R16 atomics gone = -4 (not
// epilogue). R17 cross-barrier prefetch = +4.5 (hipcc drains vmcnt(0)
// at EVERY s_barrier, m97). R18 residency x2 = -5.7 (weak). Work is
// tiny (MFMA 1.8us, VALU ~10us, HBM floor 22us) yet k2 ~110us: the
// 2-barrier-per-tile lockstep exposes full HBM latency every tile and
// FORBIDS software pipelining. Fix: 64-thread blocks = 1 wave. LDS is
// wave-private (no __syncthreads at all); next-tile adj prefetch is now
// legal -- compiler emits counted vmcnt (wait tile jt's 8 loads, keep
// jt+1's in flight), the AITER pattern. TIW=8 rows/block -> grid
// 256x8=2048 blocks = 8 independent pipelining waves/CU. MFMA A-rows
// 8-15 zeroed once (acc rows 8-15 = 0, not stored; MFMA waste is free
// at 1.4% util). Rowsum bcast via shfl(s,0) -- no LDS ordering needed.
// ~135 VGPR est, 8.4 KB LDS; grid cap 8 waves/CU is the binding limit.
__global__ __launch_bounds__(64) void gat_k2w(const int* __restrict__ adj,
                                              const unsigned short* __restrict__ ht,
                                              const float* __restrict__ f1,
                                              const float* __restrict__ f2,
                                              float* __restrict__ out) {
    __shared__ __attribute__((aligned(16))) unsigned short pb[16][TJP];  // 8.45 KB
    int lane = threadIdx.x;          // 0..63, one wave
    int i0 = blockIdx.x * TIW;
    int b = blockIdx.y;

    int mrow = lane & 15;            // MFMA m index
    int quad = lane >> 4;            // MFMA k-quad

    // zero A-rows 8..15 once (cols 0..255; pad never read by MFMA)
    ushort4 z4 = {0, 0, 0, 0};
#pragma unroll
    for (int r = 8; r < 16; ++r) *(ushort4*)&pb[r][4 * lane] = z4;

    // f1 for this block's 8 rows (same addr all lanes -> broadcast load)
    float f1r[TIW];
#pragma unroll
    for (int r = 0; r < TIW; ++r) f1r[r] = f1[(size_t)b * NN + i0 + r];

    float ps[TIW];
#pragma unroll
    for (int r = 0; r < TIW; ++r) ps[r] = 0.f;
    f32x4 acc[4];
#pragma unroll
    for (int ct = 0; ct < 4; ++ct) acc[ct] = (f32x4){0.f, 0.f, 0.f, 0.f};

    const int* adjrow = adj + (((size_t)b * NN + i0) * NN) + 4 * lane;
    const float* f2b = f2 + (size_t)b * NN + 4 * lane;
    const unsigned short* htb = ht + (size_t)b * FOUT * NN;

    // ---- prologue: issue tile 0's loads ----
    int4 av[2][TIW];
    float4 fv[2];
#pragma unroll
    for (int r = 0; r < TIW; ++r) av[0][r] = *(const int4*)(adjrow + (size_t)r * NN);
    fv[0] = *(const float4*)f2b;

#pragma unroll
    for (int jt = 0; jt < NTILE; ++jt) {   // compile-time trip; [jt&1] static
        int j0 = jt * TJ;
        int cur = jt & 1;

        // ---- prefetch tile jt+1 (no barrier -> stays in flight; counted vmcnt)
        if (jt + 1 < NTILE) {
#pragma unroll
            for (int r = 0; r < TIW; ++r)
                av[cur ^ 1][r] = *(const int4*)(adjrow + (size_t)r * NN + j0 + TJ);
            fv[cur ^ 1] = *(const float4*)(f2b + j0 + TJ);
        }

        // ---- p-phase: mask -> exp(tanh) -> bf16 into wave-private LDS ----
        float4 f = fv[cur];
#pragma unroll
        for (int r = 0; r < TIW; ++r) {
            int4 a4 = av[cur][r];
            float f1i = f1r[r];
            float4 p;
            p.x = (a4.x > 0) ? exp_tanh(f1i + f.x) : 0.f;
            p.y = (a4.y > 0) ? exp_tanh(f1i + f.y) : 0.f;
            p.z = (a4.z > 0) ? exp_tanh(f1i + f.z) : 0.f;
            p.w = (a4.w > 0) ? exp_tanh(f1i + f.w) : 0.f;
            ps[r] += p.x + p.y + p.z + p.w;
            ushort4 pk;
            pk.x = f2bf(p.x); pk.y = f2bf(p.y);
            pk.z = f2bf(p.z); pk.w = f2bf(p.w);
            *(ushort4*)&pb[r][4 * lane] = pk;
        }

        // ---- PV: 4 c-tiles x 8 K-chunks; af reused across c-tiles ----
        const unsigned short* prow = &pb[mrow][8 * quad];
#pragma unroll
        for (int ch = 0; ch < TJ / 32; ++ch) {
            bf16x8 af = *(const bf16x8*)(prow + 32 * ch);
#pragma unroll
            for (int ct = 0; ct < 4; ++ct) {
                bf16x8 bf = *(const bf16x8*)(
                    htb + (size_t)(ct * 16 + mrow) * NN + j0 + 8 * quad + 32 * ch);
                acc[ct] = __builtin_amdgcn_mfma_f32_16x16x32_bf16(af, bf, acc[ct], 0, 0, 0);
            }
        }
    }

    // ---- rowsum: shfl-reduce each of 8 rows, broadcast via lane 0 ----
    float rsw[TIW];
#pragma unroll
    for (int r = 0; r < TIW; ++r) {
        float s = ps[r];
#pragma unroll
        for (int off = 32; off > 0; off >>= 1) s += __shfl_down(s, off, 64);
        rsw[r] = __shfl(s, 0, 64);
    }

    // ---- epilogue: rows 0..7 only (D-frag row=quad*4+u, col=ct*16+mrow) ----
#pragma unroll
    for (int u = 0; u < 4; ++u) {
        int row = quad * 4 + u;
        if (row < TIW) {
            float rinv = __builtin_amdgcn_rcpf(rsw[row]);
            float* op = out + ((size_t)b * NN + i0 + row) * FOUT + mrow;
#pragma unroll
            for (int ct = 0; ct < 4; ++ct) {
                float sx = acc[ct][u] * rinv;
                op[ct * 16] = (sx > 0.f) ? sx : expm1f(sx);
            }
        }
    }
}

extern "C" void kernel_launch(void* const* d_in, const int* in_sizes, int n_in,
                              void* d_out, int out_size, void* d_ws, size_t ws_size,
                              hipStream_t stream) {
    const float* x   = (const float*)d_in[0];   // [B,N,128]
    const int*   adj = (const int*)d_in[1];     // [B,N,N]
    const float* W   = (const float*)d_in[2];   // [128,64]
    const float* a   = (const float*)d_in[3];   // [128,1]
    float* out = (float*)d_out;                 // [B,N,64]

    unsigned short* ht = (unsigned short*)d_ws;          // [B][64][2048] bf16, 2.1 MB
    float* f1   = (float*)(ht + (size_t)BB * FOUT * NN); // B*N
    float* f2   = f1 + (size_t)BB * NN;                  // B*N

    gat_k1<<<dim3(BB * NN / 16), dim3(256), 0, stream>>>(x, W, a, ht, f1, f2);
    gat_k2w<<<dim3(NN / TIW, BB), dim3(64), 0, stream>>>(adj, ht, f1, f2, out);
}

// Round 18
// 216.335 us; speedup vs baseline: 1.3718x; 1.3718x over previous
//
#include <hip/hip_runtime.h>
#include <math.h>

#define BB 8
#define NN 2048
#define FIN 128
#define FOUT 64
#define TI 16
#define TJ 256
#define TJP (TJ + 8)      // +8 bf16 = 16B row pad (verified skew family)
#define NTILE (NN / TJ)   // 8 j-tiles, looped inside the block

typedef short bf16x8 __attribute__((ext_vector_type(8)));
typedef float f32x4 __attribute__((ext_vector_type(4)));

// exp(tanh(z)) = exp((u-1)/(u+1)), u = e^{2z}; v_rcp instead of precise div.
__device__ __forceinline__ float exp_tanh(float z) {
    float zc = fminf(fmaxf(z, -15.f), 15.f);
    float u = __expf(zc + zc);
    float tn = (u - 1.f) * __builtin_amdgcn_rcpf(u + 1.f);
    return __expf(tn);
}

__device__ __forceinline__ unsigned short f2bf(float x) {
    union { float f; unsigned u; } v; v.f = x;
    unsigned r = v.u + 0x7FFF + ((v.u >> 16) & 1);   // round-to-nearest-even
    return (unsigned short)(r >> 16);
}

// K1: h = x @ W -> bf16 PANEL-MAJOR ht[b][n/32][c][n%32]; f1 = h.a1, f2 = h.a2.
// R20 delta: ht layout only. Old [b][c][n] made k2's MFMA B-load a 16-line
// gather (16 rows x 64B at 4KB stride per instruction). Panel-major makes it
// one contiguous 1KB window per wave-instruction. k1's own store improves
// too (64B-stride scatter vs 4KB).
__global__ __launch_bounds__(256, 2) void gat_k1(const float* __restrict__ x,
                                                 const float* __restrict__ W,
                                                 const float* __restrict__ a,
                                                 unsigned short* __restrict__ ht,
                                                 float* __restrict__ f1,
                                                 float* __restrict__ f2) {
    __shared__ __attribute__((aligned(16))) float Wl[FIN][FOUT];  // 32 KB
    __shared__ __attribute__((aligned(16))) float xs[16][FIN];    // 8 KB
    int t = threadIdx.x;

    const float4* W4 = (const float4*)W;
    float4* Wl4 = (float4*)&Wl[0][0];
#pragma unroll
    for (int kk = 0; kk < 8; ++kk) Wl4[t + 256 * kk] = W4[t + 256 * kk];

    size_t row0 = (size_t)blockIdx.x * 16;
    const float4* x4 = (const float4*)(x + row0 * FIN);
    float4* xs4 = (float4*)&xs[0][0];
#pragma unroll
    for (int kk = 0; kk < 2; ++kk) xs4[t + 256 * kk] = x4[t + 256 * kk];
    __syncthreads();

    int c = t & 63;
    int rq = t >> 6;
    float acc[4] = {0.f, 0.f, 0.f, 0.f};
#pragma unroll 8
    for (int k = 0; k < FIN; ++k) {
        float wv = Wl[k][c];
        acc[0] = fmaf(xs[rq][k], wv, acc[0]);
        acc[1] = fmaf(xs[rq + 4][k], wv, acc[1]);
        acc[2] = fmaf(xs[rq + 8][k], wv, acc[2]);
        acc[3] = fmaf(xs[rq + 12][k], wv, acc[3]);
    }
    float a1c = a[c], a2c = a[FOUT + c];
#pragma unroll
    for (int m = 0; m < 4; ++m) {
        size_t bn = row0 + rq + 4 * m;
        int b = (int)(bn >> 11);
        int n = (int)(bn & 2047);
        // panel-major: [b][n>>5][c][n&31]
        ht[((size_t)b * (NN / 32) + (n >> 5)) * (FOUT * 32) + c * 32 + (n & 31)] =
            f2bf(acc[m]);
        float p1 = acc[m] * a1c;
        float p2 = acc[m] * a2c;
#pragma unroll
        for (int off = 32; off > 0; off >>= 1) {
            p1 += __shfl_down(p1, off, 64);
            p2 += __shfl_down(p2, off, 64);
        }
        if (c == 0) { f1[bn] = p1; f2[bn] = p2; }
    }
}

// K2f R20: EXACT R18 structure (222.0us measured, best); ONLY the MFMA
// B-operand address changed to the panel-major ht layout.
// Ledger: R15 traffic/32=+28 (not BW; mask-k2 still ~113 w/ ZERO adj HBM
// -> floor is internal). R16 atomics gone=-4. R17 cross-barrier prefetch
// =+4.5 (vmcnt(0) drain at barriers). R18 residency x2=-5.7 (weak).
// R19 barrier-free 1-wave=+75 (worse). Last un-ablated invariant: the
// ht B-gather -- 16 cache lines per load instruction (4KB row stride),
// serialized near the MFMA. Panel-major makes each B-load one contiguous
// 1KB window; per-chunk stride FOUT*32 folds into the addressing.
__global__ __launch_bounds__(256) void gat_k2f(const int* __restrict__ adj,
                                               const unsigned short* __restrict__ ht,
                                               const float* __restrict__ f1,
                                               const float* __restrict__ f2,
                                               float* __restrict__ out) {
    __shared__ __attribute__((aligned(16))) unsigned short pb[TI][TJP];  // 8.25 KB
    __shared__ __attribute__((aligned(16))) float f2s[TJ];               // 1 KB
    __shared__ float f1s[TI];
    __shared__ float rsw[TI];                                            // 64 B

    int t = threadIdx.x;
    int i0 = blockIdx.x * TI;
    int b = blockIdx.y;

    int lane = t & 63;
    int w = t >> 6;         // wave id -> MFMA c-tile AND p-phase row group
    int mrow = lane & 15;   // MFMA m / n index
    int quad = lane >> 4;   // MFMA k-quad

    int j4 = t & 63;        // float4 col group within the 256-wide tile

    if (t < TI) f1s[t] = f1[(size_t)b * NN + i0 + t];
    __syncthreads();

    float f1r[4];
    float ps[4];
#pragma unroll
    for (int m = 0; m < 4; ++m) {
        f1r[m] = f1s[w + 4 * m];
        ps[m] = 0.f;
    }
    f32x4 acc = {0.f, 0.f, 0.f, 0.f};

    // per-thread adj base: rows (i0 + w + 4m), col group 4*j4
    const int* adjrow = adj + (((size_t)b * NN + i0) * NN) + 4 * j4;
    // panel-major ht base for this wave's c-row (w*16+mrow), k-quad offset
    const unsigned short* htb =
        ht + (size_t)b * (NN / 32) * (FOUT * 32)
           + (size_t)(w * 16 + mrow) * 32 + 8 * quad;

    for (int jt = 0; jt < NTILE; ++jt) {
        int j0 = jt * TJ;

        // adj loads for this tile (issue first; covered by f2 stage + barrier)
        int4 avreg[4];
#pragma unroll
        for (int m = 0; m < 4; ++m)
            avreg[m] = *(const int4*)(adjrow + (size_t)(w + 4 * m) * NN + j0);

        // stage this j-tile's f2 slice (256 floats, one per thread)
        f2s[t] = f2[(size_t)b * NN + j0 + t];
        __syncthreads();   // WAR barrier for pb/f2s reuse (R16-verified order)

        // ---- p-phase: mask -> exp(tanh) -> bf16 into LDS ----
        float4 fv = ((const float4*)f2s)[j4];
#pragma unroll
        for (int m = 0; m < 4; ++m) {
            int4 av = avreg[m];
            float f1i = f1r[m];
            float4 p;
            p.x = (av.x > 0) ? exp_tanh(f1i + fv.x) : 0.f;
            p.y = (av.y > 0) ? exp_tanh(f1i + fv.y) : 0.f;
            p.z = (av.z > 0) ? exp_tanh(f1i + fv.z) : 0.f;
            p.w = (av.w > 0) ? exp_tanh(f1i + fv.w) : 0.f;
            ps[m] += p.x + p.y + p.z + p.w;   // running rowsum across jt
            ushort4 pk;
            pk.x = f2bf(p.x); pk.y = f2bf(p.y);
            pk.z = f2bf(p.z); pk.w = f2bf(p.w);
            *(ushort4*)&pb[w + 4 * m][4 * j4] = pk;
        }
        __syncthreads();

        // ---- PV on matrix pipe: 8 chunks of K=32, acc chained over jt ----
        // B-load: contiguous 1KB per wave-instruction (panel-major ht)
        const unsigned short* prow = &pb[mrow][8 * quad];
        const unsigned short* hpan = htb + (size_t)(j0 >> 5) * (FOUT * 32);
#pragma unroll
        for (int ch = 0; ch < TJ / 32; ++ch) {
            bf16x8 af = *(const bf16x8*)(prow + 32 * ch);
            bf16x8 bf = *(const bf16x8*)(hpan + (size_t)ch * (FOUT * 32));
            acc = __builtin_amdgcn_mfma_f32_16x16x32_bf16(af, bf, acc, 0, 0, 0);
        }
    }

    // ---- rowsum: wave w owns rows w+4m exclusively -> one LDS write each ----
#pragma unroll
    for (int m = 0; m < 4; ++m) {
        float s = ps[m];
#pragma unroll
        for (int off = 32; off > 0; off >>= 1) s += __shfl_down(s, off, 64);
        if (lane == 0) rsw[w + 4 * m] = s;
    }
    __syncthreads();

    // ---- epilogue: final out = elu(acc / rowsum), D-frag mapping verified ----
    float* op = out + ((size_t)b * NN + i0) * FOUT + w * 16 + mrow;
#pragma unroll
    for (int u = 0; u < 4; ++u) {
        int row = quad * 4 + u;
        float rinv = __builtin_amdgcn_rcpf(rsw[row]);
        float sx = acc[u] * rinv;
        op[(size_t)row * FOUT] = (sx > 0.f) ? sx : expm1f(sx);
    }
}

extern "C" void kernel_launch(void* const* d_in, const int* in_sizes, int n_in,
                              void* d_out, int out_size, void* d_ws, size_t ws_size,
                              hipStream_t stream) {
    const float* x   = (const float*)d_in[0];   // [B,N,128]
    const int*   adj = (const int*)d_in[1];     // [B,N,N]
    const float* W   = (const float*)d_in[2];   // [128,64]
    const float* a   = (const float*)d_in[3];   // [128,1]
    float* out = (float*)d_out;                 // [B,N,64]

    unsigned short* ht = (unsigned short*)d_ws;          // [B][64][64][32] bf16, 2.1 MB
    float* f1   = (float*)(ht + (size_t)BB * FOUT * NN); // B*N
    float* f2   = f1 + (size_t)BB * NN;                  // B*N

    gat_k1<<<dim3(BB * NN / 16), dim3(256), 0, stream>>>(x, W, a, ht, f1, f2);
    gat_k2f<<<dim3(NN / TI, BB), dim3(256), 0, stream>>>(adj, ht, f1, f2, out);
}